// Round 7
// baseline (434.238 us; speedup 1.0000x reference)
//
#include <hip/hip_runtime.h>
#include <hip/hip_bf16.h>
#include <cstdint>

// Problem constants (bsz=8, h=1024, seq=1024, K=2 taps)
#define HSZ   1024
#define SEQ   1024
#define NTOT  8192      // bsz*seq
#define K2    2048      // 2*h (i,tap interleaved)

typedef __attribute__((ext_vector_type(8))) short bf16x8;
typedef __attribute__((ext_vector_type(4))) float f32x4;

__device__ __forceinline__ unsigned f2bf(float x) {
  unsigned u = __builtin_bit_cast(unsigned, x);
  return (u + 0x7fffu + ((u >> 16) & 1u)) >> 16;   // RNE, inputs are finite
}
__device__ __forceinline__ float fsig(float x)  { return 1.f / (1.f + __expf(-x)); }
__device__ __forceinline__ float ftanh(float x) { return 1.f - 2.f / (__expf(2.f * x) + 1.f); }

__device__ __forceinline__ void gload_lds16(const void* g, void* l) {
  __builtin_amdgcn_global_load_lds(
      (const __attribute__((address_space(1))) unsigned*)g,
      (__attribute__((address_space(3))) unsigned*)l, 16, 0, 0);
}

// ---- prep 1: weight fp32 -> bf16, GATE-INTERLEAVED layout ----
// Input row o = g*1024 + c  ->  output row R = c*4 + g (k layout unchanged).
__global__ void conv_weight_kernel(const float* __restrict__ w, unsigned* __restrict__ wb) {
  const int idx = (blockIdx.x * 256 + threadIdx.x) * 8;  // 4096 blocks * 2048 floats = exact
  const int o  = idx >> 11;                              // input row (g*1024+c)
  const int kk = idx & 2047;
  const int g = o >> 10, c = o & 1023;
  const int R = (c << 2) | g;                            // permuted output row
  f32x4 a = *(const f32x4*)(w + idx);
  f32x4 d = *(const f32x4*)(w + idx + 4);
  uint4 ov;
  ov.x = f2bf(a.x) | (f2bf(a.y) << 16);
  ov.y = f2bf(a.z) | (f2bf(a.w) << 16);
  ov.z = f2bf(d.x) | (f2bf(d.y) << 16);
  ov.w = f2bf(d.z) | (f2bf(d.w) << 16);
  *(uint4*)(wb + (((R << 11) | kk) >> 1)) = ov;          // kk mult of 8 -> 16B aligned
}

// ---- prep 2: Bd[n][k] bf16 (unchanged from R5 — BW-limited form) ----
__global__ void build_bdup_kernel(const float* __restrict__ z1ss, const float* __restrict__ z0,
                                  unsigned* __restrict__ bd) {
  __shared__ float tile[32 * 65];                    // [ii][c], c = local t + 1
  const int tid = threadIdx.x;
  const int n0 = blockIdx.x * 64;                    // 128 n-chunks (never cross batch)
  const int i0 = blockIdx.y * 32;                    // 32 i-chunks
  const int b  = n0 >> 10;
  const int t0 = n0 & 1023;
  const int l16 = tid & 15, r16 = tid >> 4;          // 16 rows per pass, 2 passes
#pragma unroll
  for (int pr = 0; pr < 2; ++pr) {
    const int ii = r16 + pr * 16;
    const float* zrow = z1ss + (size_t)(b * 2048 + i0 + ii) * 1024;
    f32x4 v = *(const f32x4*)(zrow + t0 + l16 * 4);
    float* tr = tile + ii * 65 + 1 + l16 * 4;
    tr[0] = v.x; tr[1] = v.y; tr[2] = v.z; tr[3] = v.w;
    if (l16 == 0)
      tile[ii * 65] = t0 ? zrow[t0 - 1] : z0[b * 2048 + i0 + ii];
  }
  __syncthreads();
  const int i2 = tid & 31, ts = tid >> 5;
#pragma unroll
  for (int p = 0; p < 8; ++p) {
    const int tt = ts + p * 8;
    float prev = tile[i2 * 65 + tt];                 // x[t0+tt-1] (or z0h)
    float cur  = tile[i2 * 65 + tt + 1];             // x[t0+tt]
    bd[(size_t)(n0 + tt) * 1024 + i0 + i2] = f2bf(prev) | (f2bf(cur) << 16);
  }
}

// ---- GEMM + fused LSTM epilogue ----
// 128x128 block, 64x64 waves (2x2), gate-interleaved A (R6, proven 188 us),
// restructured K-loop: BK=32 with 2-buffer ping-pong and ONE plain
// __syncthreads per step:
//   stage(t+1) -> buf^1 (4 gload_lds, issued FIRST)
//   compute(t) from buf  (8 ds_read_b128 + 16 MFMA, ~400 cy)
//   __syncthreads()      (vmcnt drain now covers loads issued BEFORE compute)
// Same resources as R6 (LDS 32 KB = 2 x {A 8KB + B 8KB}, fewer staging regs),
// same barrier count (64), but the drain is pre-covered by compute instead of
// exposed. Race audit: stage(t+1) writes buf^1 whose step-(t-1) readers all
// passed barrier(t-1); barrier(t) retires buf(t) readers + drains stage(t+1).
// LDS layout per tile: [128 rows][4 slots of 8 shorts], slot = chunk^((row>>1)&3)
// -> DMA-linear dest + pre-swizzled source (rule 21); read rows have
// row&15 == l15 so read slot = quad ^ ((l15>>1)&3); measured 0 conflicts (R0).
__launch_bounds__(256, 3)
__global__ void lstm_gemm_kernel(const unsigned short* __restrict__ Wb,
                                 const unsigned short* __restrict__ Bd,
                                 const float* __restrict__ uss,
                                 const float* __restrict__ z1ss,
                                 const float* __restrict__ z0,
                                 const float* __restrict__ bias,
                                 float* __restrict__ out) {
  __shared__ unsigned short Asm_[2 * 128 * 32];   // 2 bufs x 8 KB, swizzled
  __shared__ unsigned short Bsm_[2 * 128 * 32];   // 2 bufs x 8 KB, swizzled
  const int tid  = threadIdx.x;
  const int wave = tid >> 6, lane = tid & 63;
  const int l15  = lane & 15, quad = lane >> 4;
  const int wm   = wave >> 1, wn = wave & 1;  // 2x2 wave grid
  const int c0 = blockIdx.y * 32;             // channel tile
  const int n0 = blockIdx.x * 128;

  // staging: per wave 2 A-insts + 2 B-insts, each covers 16 rows x 32k (1 KiB)
  // unit u = (wave*2+j)*64+lane; row = u>>2 in [0,128), slot = u&3;
  // global chunk = slot ^ ((row>>1)&3)  (pre-swizzled source).
  const unsigned short *aG[2], *bG[2];
  int sOfs[2];
#pragma unroll
  for (int j = 0; j < 2; ++j) {
    const int u = (wave * 2 + j) * 64 + lane;
    const int row = u >> 2;
    const int ck = ((u & 3) ^ ((row >> 1) & 3)) * 8;
    aG[j] = Wb + (size_t)(c0 * 4 + row) * K2 + ck;   // contiguous gate-interleaved panel
    bG[j] = Bd + (size_t)(n0 + row) * K2 + ck;
    sOfs[j] = (wave * 2 + j) * 512;                  // shorts offset within a buffer
  }

  // fragment read slot: read rows r have r&15 == l15 -> (r>>1)&3 = (l15>>1)&3
  const int slot = ((quad ^ ((l15 >> 1) & 3)) << 3); // shorts offset of 16B chunk

  f32x4 acc[4][4];
#pragma unroll
  for (int m = 0; m < 4; ++m)
#pragma unroll
    for (int nt = 0; nt < 4; ++nt)
      acc[m][nt] = (f32x4){0.f, 0.f, 0.f, 0.f};

  // per-step bodies with compile-time buffer selection (rule 20: static idx)
  auto stage = [&](int buf, int k0) {
#pragma unroll
    for (int j = 0; j < 2; ++j) gload_lds16(aG[j] + k0, Asm_ + buf * 4096 + sOfs[j]);
#pragma unroll
    for (int j = 0; j < 2; ++j) gload_lds16(bG[j] + k0, Bsm_ + buf * 4096 + sOfs[j]);
  };
  auto compute = [&](int buf) {
    const unsigned short* At = Asm_ + buf * 4096;
    const unsigned short* Bt = Bsm_ + buf * 4096;
    bf16x8 bf[4];
#pragma unroll
    for (int nt = 0; nt < 4; ++nt)
      bf[nt] = *(const bf16x8*)(Bt + (wn * 64 + nt * 16 + l15) * 32 + slot);
#pragma unroll
    for (int m = 0; m < 4; ++m) {
      bf16x8 af = *(const bf16x8*)(At + (wm * 64 + m * 16 + l15) * 32 + slot);
#pragma unroll
      for (int nt = 0; nt < 4; ++nt)
        acc[m][nt] = __builtin_amdgcn_mfma_f32_16x16x32_bf16(af, bf[nt], acc[m][nt], 0, 0, 0);
    }
  };

  // prologue: stage tile 0
  stage(0, 0);
  __syncthreads();

  // main loop: 64 K-steps of 32, 2-step bodies for static buffer indices.
  // steps 0..61 always stage; 62 stages 63; 63 stages nothing.
  for (int t = 0; t < 62; t += 2) {
    stage(1, (t + 1) * 32);
    compute(0);
    __syncthreads();
    stage(0, (t + 2) * 32);
    compute(1);
    __syncthreads();
  }
  stage(1, 63 * 32);
  compute(0);
  __syncthreads();
  compute(1);

  // epilogue: C/D col=l15 (n), row=quad*4+r; gate-interleave => gate g == r.
#pragma unroll
  for (int m = 0; m < 4; ++m) {
    const int ch = c0 + wm * 16 + m * 4 + quad;
    const float bv0 = bias[ch], bv1 = bias[1024 + ch], bv2 = bias[2048 + ch], bv3 = bias[3072 + ch];
#pragma unroll
    for (int nt = 0; nt < 4; ++nt) {
      const int n = n0 + wn * 64 + nt * 16 + l15;
      const int b = n >> 10, t = n & 1023;
      const int ub = b * 4194304 + ch * 1024 + t;    // uss[b][g*1024+ch][t], gate stride 1048576
      f32x4 ac = acc[m][nt];
      float p0 = ac.x + uss[ub]           + bv0;     // gate i (g=0)
      float p1 = ac.y + uss[ub + 1048576] + bv1;     // gate o (g=1)
      float p2 = ac.z + uss[ub + 2097152] + bv2;     // gate g (g=2)
      float p3 = ac.w + uss[ub + 3145728] + bv3;     // gate f (g=3)
      float it = fsig(p0), ot = fsig(p1), g_ = ftanh(p2), ft = fsig(p3);
      float zc = t ? z1ss[(b * 2048 + 1024 + ch) * 1024 + t - 1]
                   : z0[b * 2048 + 1024 + ch];
      float ct = ft * zc + it * g_;
      float ht = ot * ftanh(ct);
      const int ob = (b * 2048 + ch) * 1024 + t;
      out[ob] = ht;
      out[ob + 1048576] = ct;
    }
  }
}

// ---- slow-but-correct fallback if ws too small ----
__global__ void naive_kernel(const float* __restrict__ z1ss, const float* __restrict__ uss,
                             const float* __restrict__ z0, const float* __restrict__ w,
                             const float* __restrict__ bias, float* __restrict__ out) {
  int idx = blockIdx.x * 256 + threadIdx.x;          // (b,c,t)
  int b = idx >> 20, c = (idx >> 10) & 1023, t = idx & 1023;
  float s0 = 0.f, s1 = 0.f, s2 = 0.f, s3 = 0.f;
  const float* xb = z1ss + b * 2097152;
  for (int i = 0; i < 1024; ++i) {
    float cur  = xb[i * 1024 + t];
    float prev = t ? xb[i * 1024 + t - 1] : z0[b * 2048 + i];
    const float* wr = w + c * 2048 + i * 2;
    s0 += wr[0]       * prev + wr[1]       * cur;
    s1 += wr[2097152] * prev + wr[2097153] * cur;
    s2 += wr[4194304] * prev + wr[4194305] * cur;
    s3 += wr[6291456] * prev + wr[6291457] * cur;
  }
  int ub = b * 4194304 + c * 1024 + t;
  float p0 = s0 + uss[ub]           + bias[c];
  float p1 = s1 + uss[ub + 1048576] + bias[1024 + c];
  float p2 = s2 + uss[ub + 2097152] + bias[2048 + c];
  float p3 = s3 + uss[ub + 3145728] + bias[3072 + c];
  float it = fsig(p0), ot = fsig(p1), g_ = ftanh(p2), ft = fsig(p3);
  float zc = t ? z1ss[(b * 2048 + 1024 + c) * 1024 + t - 1] : z0[b * 2048 + 1024 + c];
  float ct = ft * zc + it * g_;
  float ht = ot * ftanh(ct);
  int ob = (b * 2048 + c) * 1024 + t;
  out[ob] = ht;
  out[ob + 1048576] = ct;
}

extern "C" void kernel_launch(void* const* d_in, const int* in_sizes, int n_in,
                              void* d_out, int out_size, void* d_ws, size_t ws_size,
                              hipStream_t stream) {
  const float* z1ss = (const float*)d_in[0];
  const float* uss  = (const float*)d_in[1];
  const float* z0   = (const float*)d_in[2];
  const float* w    = (const float*)d_in[3];
  const float* bias = (const float*)d_in[4];
  float* out = (float*)d_out;

  const size_t needWb = (size_t)4096 * 2048 * 2;   // 16 MB bf16 weight
  const size_t needBd = (size_t)NTOT * K2 * 2;     // 32 MB bf16 B matrix
  if (ws_size >= needWb + needBd) {
    unsigned short* Wb = (unsigned short*)d_ws;
    unsigned short* Bd = Wb + (size_t)4096 * 2048;
    conv_weight_kernel<<<4096, 256, 0, stream>>>(w, (unsigned*)Wb);
    build_bdup_kernel<<<dim3(128, 32), 256, 0, stream>>>(z1ss, z0, (unsigned*)Bd);
    lstm_gemm_kernel<<<dim3(64, 32), 256, 0, stream>>>(Wb, Bd, uss, z1ss, z0, bias, out);
  } else {
    naive_kernel<<<32768, 256, 0, stream>>>(z1ss, uss, z0, w, bias, out);
  }
}